// Round 7
// baseline (170.120 us; speedup 1.0000x reference)
//
#include <hip/hip_runtime.h>
#include <hip/hip_bf16.h>
#include <math.h>

// NonLocalEncoder 'sharing': M=N=768, C=256, IMG=1024, CAT=1792
#define MM 768
#define CC 256
#define EPSV 1e-4f

__device__ __forceinline__ float sigmoidf_(float x) { return 1.0f / (1.0f + expf(-x)); }

// ===========================================================================
// Kernel A (grid 1928 x 256): fused independent preprocessing
//   blocks [0,1536)   : conflict max-pool (ballot compaction + 4-acc gather)
//   blocks [1536,1920): pred0 heads, 4 rows/block -> out[0:1536)
//   blocks [1920,1928): img-bias partials (image slab of W -> constant [256])
// ===========================================================================
__global__ __launch_bounds__(256) void k_prep(
    const float* __restrict__ edge_x, const float* __restrict__ loop_x,
    const float* __restrict__ image_x,
    const float* __restrict__ ecm, const float* __restrict__ lcm,
    const float* __restrict__ We3, const float* __restrict__ Wl3,
    const float* __restrict__ Wep1, const float* __restrict__ bep1,
    const float* __restrict__ Wep2, const float* __restrict__ bep2,
    const float* __restrict__ Wlp1, const float* __restrict__ blp1,
    const float* __restrict__ Wlp2, const float* __restrict__ blp2,
    float* __restrict__ out, float* __restrict__ efc, float* __restrict__ lfc,
    float* __restrict__ imgpart)
{
    int bid = blockIdx.x;
    int t   = threadIdx.x;

    if (bid < 1536) {
        __shared__ int   s_cnt;
        __shared__ int   s_idx[MM];
        __shared__ float s_val[MM];
        bool isLoop = bid >= MM;
        int  m      = bid & (MM - 1);
        const float* mask = isLoop ? lcm : ecm;
        const float* x    = isLoop ? loop_x : edge_x;
        float*       o    = isLoop ? lfc : efc;

        if (t == 0) s_cnt = 0;
        __syncthreads();
        int lane = t & 63;
        #pragma unroll
        for (int r = 0; r < 3; ++r) {
            int j = t + r * 256;
            float v = mask[m * MM + j];
            bool nz = (v != 0.0f);
            unsigned long long b = __ballot(nz);
            int prefix = __popcll(b & ((1ull << lane) - 1ull));
            int cntw   = __popcll(b);
            int base = 0;
            if (lane == 0 && cntw) base = atomicAdd(&s_cnt, cntw);
            base = __shfl(base, 0, 64);
            if (nz) { s_idx[base + prefix] = j; s_val[base + prefix] = v; }
        }
        __syncthreads();
        int cnt = s_cnt;
        float init = (cnt < MM) ? 0.0f : -INFINITY;
        float a0 = init, a1 = init, a2 = init, a3 = init;
        int i = 0;
        for (; i + 4 <= cnt; i += 4) {
            a0 = fmaxf(a0, s_val[i + 0] * x[s_idx[i + 0] * CC + t]);
            a1 = fmaxf(a1, s_val[i + 1] * x[s_idx[i + 1] * CC + t]);
            a2 = fmaxf(a2, s_val[i + 2] * x[s_idx[i + 2] * CC + t]);
            a3 = fmaxf(a3, s_val[i + 3] * x[s_idx[i + 3] * CC + t]);
        }
        for (; i < cnt; ++i)
            a0 = fmaxf(a0, s_val[i] * x[s_idx[i] * CC + t]);
        o[m * CC + t] = fmaxf(fmaxf(a0, a1), fmaxf(a2, a3));

    } else if (bid < 1920) {
        int wave = t >> 6, lane = t & 63;
        int row  = (bid - 1536) * 4 + wave;          // 0..1535
        const float *x, *W1, *b1, *W2;
        float b2v;
        if (row < MM) { x = edge_x + row * CC;        W1 = Wep1; b1 = bep1; W2 = Wep2; b2v = bep2[0]; }
        else          { x = loop_x + (row - MM) * CC; W1 = Wlp1; b1 = blp1; W2 = Wlp2; b2v = blp2[0]; }

        float a0 = 0.f, a1 = 0.f, a2 = 0.f, a3 = 0.f;
        for (int cc = 0; cc < CC; cc += 4) {
            float4 xv = *reinterpret_cast<const float4*>(x + cc);
            a0 = fmaf(xv.x, W1[(cc + 0) * 64 + lane], a0);
            a1 = fmaf(xv.y, W1[(cc + 1) * 64 + lane], a1);
            a2 = fmaf(xv.z, W1[(cc + 2) * 64 + lane], a2);
            a3 = fmaf(xv.w, W1[(cc + 3) * 64 + lane], a3);
        }
        float h = fmaxf(b1[lane] + ((a0 + a1) + (a2 + a3)), 0.0f);
        float p = h * W2[lane];
        #pragma unroll
        for (int off = 32; off; off >>= 1) p += __shfl_xor(p, off, 64);
        if (lane == 0) out[row] = sigmoidf_(p + b2v);

    } else {
        int sub   = bid - 1920;       // 0..7
        int chunk = sub & 3;
        int head  = sub >> 2;
        const float* W = head ? Wl3 : We3;
        int k0 = chunk * 256;
        float s = 0.0f;
        #pragma unroll 4
        for (int k = 0; k < 256; ++k)
            s = fmaf(image_x[k0 + k], W[(768 + k0 + k) * CC + t], s);
        imgpart[head * 1024 + chunk * 256 + t] = s;
    }
}

// ===========================================================================
// Kernel B (grid 768 x 512): weighted broadcast sums, split over s-halves.
//   bid: pair = bid>>1 (0..383), sh = bid&1 (which s-half of 384)
//        pair<192 -> efl rows (4 per pair); else lfe rows.
// Phase 1: FULL w-slice (768 x 4) into LDS + full normalization sums
//          (identical in both sh-blocks -> deterministic).
// Phase 2: 8 waves each own 48 s-values of this block's s-half; float4 x
//          loads (lane = c4), wave-uniform b128 w broadcast; acc[4][4]/thread.
// Reduce:  LDS tree across waves; wave 0 divides by sums and stores this
//          half's PARTIAL to its own buffer. k_cat adds the two partials.
// ===========================================================================
__global__ __launch_bounds__(512) void k_bsum(
    const float* __restrict__ lem, const float* __restrict__ edge_x,
    const float* __restrict__ loop_x, const float* __restrict__ pred,
    float* __restrict__ efl_p0, float* __restrict__ efl_p1,
    float* __restrict__ lfe_p0, float* __restrict__ lfe_p1)
{
    __shared__ float4 s_wv4[MM];       // 12KB: w[s][0..3]
    __shared__ float  s_pw[8 * 4];
    __shared__ float  s_sum[4];
    __shared__ float  s_red[4 * 16 * 64];  // 16KB reduce scratch
    float* s_wv = reinterpret_cast<float*>(s_wv4);

    int bid  = blockIdx.x;
    int t    = threadIdx.x;
    int pair = bid >> 1, sh = bid & 1;
    const float* e0 = pred;
    const float* l0 = pred + MM;

    bool isE = pair < 192;
    int  r0  = (isE ? pair : pair - 192) * 4;
    const float* ownp = isE ? e0 : l0;
    const float* othp = isE ? l0 : e0;

    float own0 = ownp[r0], own1 = ownp[r0 + 1], own2 = ownp[r0 + 2], own3 = ownp[r0 + 3];

    // ---- phase 1: full w-slice + full sums ----
    int i_ = t & 3;
    float myown = own0;
    if (i_ == 1) myown = own1; else if (i_ == 2) myown = own2; else if (i_ == 3) myown = own3;
    float psum = 0.f;
    #pragma unroll
    for (int k = 0; k < 6; ++k) {
        int idx = t + k * 512;
        int s = idx >> 2;
        float lm = isE ? lem[s * MM + r0 + i_] : lem[(r0 + i_) * MM + s];
        float wv = lm * fabsf(othp[s] - myown);
        s_wv[idx] = wv;
        psum += wv;
    }
    #pragma unroll
    for (int off = 4; off < 64; off <<= 1) psum += __shfl_xor(psum, off, 64);
    int wave = t >> 6, lane = t & 63;
    if (lane < 4) s_pw[wave * 4 + lane] = psum;
    __syncthreads();
    if (t < 4) {
        float s = 0.f;
        #pragma unroll
        for (int w = 0; w < 8; ++w) s += s_pw[w * 4 + t];
        s_sum[t] = fmaxf(s, EPSV);
    }

    // ---- phase 2: this half's s-range, wave-sliced ----
    const float* xsrc = isE ? loop_x : edge_x;
    int s_base = sh * 384 + wave * 48;
    float acc[4][4];
    #pragma unroll
    for (int i = 0; i < 4; ++i)
        #pragma unroll
        for (int c = 0; c < 4; ++c) acc[i][c] = 0.f;

    #pragma unroll 4
    for (int j = 0; j < 48; ++j) {
        int s = s_base + j;
        float4 w4 = s_wv4[s];                                   // uniform broadcast
        float4 xv = *reinterpret_cast<const float4*>(xsrc + s * CC + lane * 4);
        acc[0][0] = fmaf(w4.x, xv.x, acc[0][0]); acc[0][1] = fmaf(w4.x, xv.y, acc[0][1]);
        acc[0][2] = fmaf(w4.x, xv.z, acc[0][2]); acc[0][3] = fmaf(w4.x, xv.w, acc[0][3]);
        acc[1][0] = fmaf(w4.y, xv.x, acc[1][0]); acc[1][1] = fmaf(w4.y, xv.y, acc[1][1]);
        acc[1][2] = fmaf(w4.y, xv.z, acc[1][2]); acc[1][3] = fmaf(w4.y, xv.w, acc[1][3]);
        acc[2][0] = fmaf(w4.z, xv.x, acc[2][0]); acc[2][1] = fmaf(w4.z, xv.y, acc[2][1]);
        acc[2][2] = fmaf(w4.z, xv.z, acc[2][2]); acc[2][3] = fmaf(w4.z, xv.w, acc[2][3]);
        acc[3][0] = fmaf(w4.w, xv.x, acc[3][0]); acc[3][1] = fmaf(w4.w, xv.y, acc[3][1]);
        acc[3][2] = fmaf(w4.w, xv.z, acc[3][2]); acc[3][3] = fmaf(w4.w, xv.w, acc[3][3]);
    }

    // ---- tree reduce 8 -> 4 -> 2 -> 1 waves ----
    if (wave >= 4) {
        #pragma unroll
        for (int i = 0; i < 4; ++i)
            #pragma unroll
            for (int c = 0; c < 4; ++c)
                s_red[(wave - 4) * 1024 + (i * 4 + c) * 64 + lane] = acc[i][c];
    }
    __syncthreads();
    if (wave < 4) {
        #pragma unroll
        for (int i = 0; i < 4; ++i)
            #pragma unroll
            for (int c = 0; c < 4; ++c)
                acc[i][c] += s_red[wave * 1024 + (i * 4 + c) * 64 + lane];
    }
    __syncthreads();
    if (wave == 2 || wave == 3) {
        #pragma unroll
        for (int i = 0; i < 4; ++i)
            #pragma unroll
            for (int c = 0; c < 4; ++c)
                s_red[(wave - 2) * 1024 + (i * 4 + c) * 64 + lane] = acc[i][c];
    }
    __syncthreads();
    if (wave < 2) {
        #pragma unroll
        for (int i = 0; i < 4; ++i)
            #pragma unroll
            for (int c = 0; c < 4; ++c)
                acc[i][c] += s_red[wave * 1024 + (i * 4 + c) * 64 + lane];
    }
    __syncthreads();
    if (wave == 1) {
        #pragma unroll
        for (int i = 0; i < 4; ++i)
            #pragma unroll
            for (int c = 0; c < 4; ++c)
                s_red[(i * 4 + c) * 64 + lane] = acc[i][c];
    }
    __syncthreads();
    if (wave == 0) {
        float* outp = isE ? (sh ? efl_p1 : efl_p0) : (sh ? lfe_p1 : lfe_p0);
        #pragma unroll
        for (int i = 0; i < 4; ++i) {
            float inv = 1.0f / s_sum[i];
            float4 o;
            o.x = (acc[i][0] + s_red[(i * 4 + 0) * 64 + lane]) * inv;
            o.y = (acc[i][1] + s_red[(i * 4 + 1) * 64 + lane]) * inv;
            o.z = (acc[i][2] + s_red[(i * 4 + 2) * 64 + lane]) * inv;
            o.w = (acc[i][3] + s_red[(i * 4 + 3) * 64 + lane]) * inv;
            *reinterpret_cast<float4*>(outp + (r0 + i) * CC + lane * 4) = o;
        }
    }
}

// ===========================================================================
// Kernel C (grid (192,2) x 512): x2 = relu(cat @ W + b) fused with pred1.
// 4 output rows/block; 8 waves each own 96 k of the 768 non-image concat
// rows; float4 W loads (lane = c4), wave-uniform float4 x loads; LDS tree
// reduce; wave 0 applies bias(+img)+relu into s_act; all waves run pred1.
// x_from_other arrives as two s-half partials (added here).
// ===========================================================================
__global__ __launch_bounds__(512) void k_cat(
    const float* __restrict__ edge_x, const float* __restrict__ loop_x,
    const float* __restrict__ efl_p0, const float* __restrict__ efl_p1,
    const float* __restrict__ lfe_p0, const float* __restrict__ lfe_p1,
    const float* __restrict__ efc, const float* __restrict__ lfc,
    const float* __restrict__ We3, const float* __restrict__ be3,
    const float* __restrict__ Wl3, const float* __restrict__ bl3,
    const float* __restrict__ imgpart,
    const float* __restrict__ Wep1, const float* __restrict__ bep1,
    const float* __restrict__ Wep2, const float* __restrict__ bep2,
    const float* __restrict__ Wlp1, const float* __restrict__ blp1,
    const float* __restrict__ Wlp2, const float* __restrict__ blp2,
    float* __restrict__ out)
{
    __shared__ float s_red[4 * 16 * 64];  // 16KB
    __shared__ float s_act[4 * CC];       // 4KB
    __shared__ float s_h[8 * 64];         // 2KB

    int head = blockIdx.y;
    const float* W   = head ? Wl3 : We3;
    const float* b   = head ? bl3 : be3;
    const float* x0  = head ? loop_x : edge_x;
    const float* x1a = head ? lfe_p0 : efl_p0;
    const float* x1b = head ? lfe_p1 : efl_p1;
    const float* x2  = head ? lfc : efc;
    const float* ip  = imgpart + head * 1024;

    int m0 = blockIdx.x * 4;
    int t  = threadIdx.x;
    int wave = t >> 6, lane = t & 63;

    float acc[4][4];
    #pragma unroll
    for (int i = 0; i < 4; ++i)
        #pragma unroll
        for (int c = 0; c < 4; ++c) acc[i][c] = 0.f;

    int k0 = wave * 96;
    for (int jj = 0; jj < 96; jj += 4) {
        int k = k0 + jj;
        float4 xr[4];
        if (k < 256) {
            #pragma unroll
            for (int i = 0; i < 4; ++i)
                xr[i] = *reinterpret_cast<const float4*>(x0 + (m0 + i) * CC + k);
        } else if (k < 512) {
            int kk = k - 256;
            #pragma unroll
            for (int i = 0; i < 4; ++i) {
                float4 a = *reinterpret_cast<const float4*>(x1a + (m0 + i) * CC + kk);
                float4 bb = *reinterpret_cast<const float4*>(x1b + (m0 + i) * CC + kk);
                xr[i].x = a.x + bb.x; xr[i].y = a.y + bb.y;
                xr[i].z = a.z + bb.z; xr[i].w = a.w + bb.w;
            }
        } else {
            int kk = k - 512;
            #pragma unroll
            for (int i = 0; i < 4; ++i)
                xr[i] = *reinterpret_cast<const float4*>(x2 + (m0 + i) * CC + kk);
        }
        #pragma unroll
        for (int j = 0; j < 4; ++j) {
            float4 wv = *reinterpret_cast<const float4*>(W + (k + j) * CC + lane * 4);
            float xj0 = reinterpret_cast<const float*>(&xr[0])[j];
            float xj1 = reinterpret_cast<const float*>(&xr[1])[j];
            float xj2 = reinterpret_cast<const float*>(&xr[2])[j];
            float xj3 = reinterpret_cast<const float*>(&xr[3])[j];
            acc[0][0] = fmaf(xj0, wv.x, acc[0][0]); acc[0][1] = fmaf(xj0, wv.y, acc[0][1]);
            acc[0][2] = fmaf(xj0, wv.z, acc[0][2]); acc[0][3] = fmaf(xj0, wv.w, acc[0][3]);
            acc[1][0] = fmaf(xj1, wv.x, acc[1][0]); acc[1][1] = fmaf(xj1, wv.y, acc[1][1]);
            acc[1][2] = fmaf(xj1, wv.z, acc[1][2]); acc[1][3] = fmaf(xj1, wv.w, acc[1][3]);
            acc[2][0] = fmaf(xj2, wv.x, acc[2][0]); acc[2][1] = fmaf(xj2, wv.y, acc[2][1]);
            acc[2][2] = fmaf(xj2, wv.z, acc[2][2]); acc[2][3] = fmaf(xj2, wv.w, acc[2][3]);
            acc[3][0] = fmaf(xj3, wv.x, acc[3][0]); acc[3][1] = fmaf(xj3, wv.y, acc[3][1]);
            acc[3][2] = fmaf(xj3, wv.z, acc[3][2]); acc[3][3] = fmaf(xj3, wv.w, acc[3][3]);
        }
    }

    // ---- tree reduce 8 -> 4 -> 2 -> 1 ----
    if (wave >= 4) {
        #pragma unroll
        for (int i = 0; i < 4; ++i)
            #pragma unroll
            for (int c = 0; c < 4; ++c)
                s_red[(wave - 4) * 1024 + (i * 4 + c) * 64 + lane] = acc[i][c];
    }
    __syncthreads();
    if (wave < 4) {
        #pragma unroll
        for (int i = 0; i < 4; ++i)
            #pragma unroll
            for (int c = 0; c < 4; ++c)
                acc[i][c] += s_red[wave * 1024 + (i * 4 + c) * 64 + lane];
    }
    __syncthreads();
    if (wave == 2 || wave == 3) {
        #pragma unroll
        for (int i = 0; i < 4; ++i)
            #pragma unroll
            for (int c = 0; c < 4; ++c)
                s_red[(wave - 2) * 1024 + (i * 4 + c) * 64 + lane] = acc[i][c];
    }
    __syncthreads();
    if (wave < 2) {
        #pragma unroll
        for (int i = 0; i < 4; ++i)
            #pragma unroll
            for (int c = 0; c < 4; ++c)
                acc[i][c] += s_red[wave * 1024 + (i * 4 + c) * 64 + lane];
    }
    __syncthreads();
    if (wave == 1) {
        #pragma unroll
        for (int i = 0; i < 4; ++i)
            #pragma unroll
            for (int c = 0; c < 4; ++c)
                s_red[(i * 4 + c) * 64 + lane] = acc[i][c];
    }
    __syncthreads();
    if (wave == 0) {
        float4 b4  = *reinterpret_cast<const float4*>(b + lane * 4);
        float4 i0  = *reinterpret_cast<const float4*>(ip + lane * 4);
        float4 i1  = *reinterpret_cast<const float4*>(ip + 256 + lane * 4);
        float4 i2  = *reinterpret_cast<const float4*>(ip + 512 + lane * 4);
        float4 i3  = *reinterpret_cast<const float4*>(ip + 768 + lane * 4);
        float bias[4] = { b4.x + i0.x + i1.x + i2.x + i3.x,
                          b4.y + i0.y + i1.y + i2.y + i3.y,
                          b4.z + i0.z + i1.z + i2.z + i3.z,
                          b4.w + i0.w + i1.w + i2.w + i3.w };
        #pragma unroll
        for (int i = 0; i < 4; ++i) {
            float4 o;
            o.x = fmaxf(acc[i][0] + s_red[(i * 4 + 0) * 64 + lane] + bias[0], 0.f);
            o.y = fmaxf(acc[i][1] + s_red[(i * 4 + 1) * 64 + lane] + bias[1], 0.f);
            o.z = fmaxf(acc[i][2] + s_red[(i * 4 + 2) * 64 + lane] + bias[2], 0.f);
            o.w = fmaxf(acc[i][3] + s_red[(i * 4 + 3) * 64 + lane] + bias[3], 0.f);
            *reinterpret_cast<float4*>(s_act + i * CC + lane * 4) = o;
        }
    }
    __syncthreads();

    // ---- fused pred1: wave pair per row (row = wave>>1, khalf = wave&1) ----
    int row = wave >> 1, khalf = wave & 1;
    const float* W1 = head ? Wlp1 : Wep1;
    const float* b1 = head ? blp1 : bep1;
    const float* W2 = head ? Wlp2 : Wep2;
    float b2v       = head ? blp2[0] : bep2[0];
    const float* xr = s_act + row * CC + khalf * 128;

    float a0 = 0.f, a1 = 0.f, a2 = 0.f, a3 = 0.f;
    for (int cc = 0; cc < 128; cc += 4) {
        float4 xv = *reinterpret_cast<const float4*>(xr + cc);
        int kb = khalf * 128 + cc;
        a0 = fmaf(xv.x, W1[(kb + 0) * 64 + lane], a0);
        a1 = fmaf(xv.y, W1[(kb + 1) * 64 + lane], a1);
        a2 = fmaf(xv.z, W1[(kb + 2) * 64 + lane], a2);
        a3 = fmaf(xv.w, W1[(kb + 3) * 64 + lane], a3);
    }
    s_h[wave * 64 + lane] = (a0 + a1) + (a2 + a3);
    __syncthreads();
    if (khalf == 0) {
        float hv = fmaxf(b1[lane] + s_h[wave * 64 + lane] + s_h[(wave + 1) * 64 + lane], 0.0f);
        float p = hv * W2[lane];
        #pragma unroll
        for (int off = 32; off; off >>= 1) p += __shfl_xor(p, off, 64);
        if (lane == 0) out[1536 + head * MM + m0 + row] = sigmoidf_(p + b2v);
    }
}

// ===========================================================================
extern "C" void kernel_launch(void* const* d_in, const int* in_sizes, int n_in,
                              void* d_out, int out_size, void* d_ws, size_t ws_size,
                              hipStream_t stream)
{
    const float* edge_x  = (const float*)d_in[0];
    const float* loop_x  = (const float*)d_in[1];
    const float* image_x = (const float*)d_in[2];
    const float* lem     = (const float*)d_in[3];
    const float* ecm     = (const float*)d_in[4];
    const float* lcm     = (const float*)d_in[5];
    // d_in[6..8] unused
    const float* We3  = (const float*)d_in[9];
    const float* be3  = (const float*)d_in[10];
    const float* Wl3  = (const float*)d_in[11];
    const float* bl3  = (const float*)d_in[12];
    const float* Wep1 = (const float*)d_in[13];
    const float* bep1 = (const float*)d_in[14];
    const float* Wep2 = (const float*)d_in[15];
    const float* bep2 = (const float*)d_in[16];
    const float* Wlp1 = (const float*)d_in[17];
    const float* blp1 = (const float*)d_in[18];
    const float* Wlp2 = (const float*)d_in[19];
    const float* blp2 = (const float*)d_in[20];

    float* out = (float*)d_out;          // [3072] = e0 | l0 | e1 | l1
    float* ws  = (float*)d_ws;

    // workspace (floats):
    float* imgpart = ws;                       // 2048
    float* efl_p0  = ws + 2048;
    float* efl_p1  = efl_p0 + MM * CC;
    float* lfe_p0  = efl_p1 + MM * CC;
    float* lfe_p1  = lfe_p0 + MM * CC;
    float* efc     = lfe_p1 + MM * CC;
    float* lfc     = efc + MM * CC;            // total ~4.7 MB

    // A: conflict pools + pred0 + img-bias (independent)
    k_prep<<<1928, 256, 0, stream>>>(edge_x, loop_x, image_x, ecm, lcm,
                                     We3, Wl3,
                                     Wep1, bep1, Wep2, bep2,
                                     Wlp1, blp1, Wlp2, blp2,
                                     out, efc, lfc, imgpart);

    // B: weighted broadcast sums, s-split partials (reads e0/l0 from out)
    k_bsum<<<768, 512, 0, stream>>>(lem, edge_x, loop_x, out,
                                    efl_p0, efl_p1, lfe_p0, lfe_p1);

    // C: concat-GEMM + relu + fused pred1 (adds the s-half partials)
    k_cat<<<dim3(192, 2), 512, 0, stream>>>(edge_x, loop_x,
                                            efl_p0, efl_p1, lfe_p0, lfe_p1,
                                            efc, lfc,
                                            We3, be3, Wl3, bl3, imgpart,
                                            Wep1, bep1, Wep2, bep2,
                                            Wlp1, blp1, Wlp2, blp2, out);
}